// Round 8
// baseline (446.436 us; speedup 1.0000x reference)
//
#include <hip/hip_runtime.h>
#include <math.h>

// N=262144, D=128, C=1024. Embeddings fp32, output fp32 scalar, labels int32
// (int64 tolerated via uniform high-word probe).
//
// R3/R5/R7 established: ~262K random row-sized accesses cost ~90-100 us on
// this machine regardless of granule (256/512 B), direction (R/W), or
// in-kernel MLP -> address-translation/page wall (~360 ns/random page).
// Therefore: NO fine-grained random access anywhere. 8-bucket two-phase
// privatized reduction; all heavy traffic is sequential or >=32 KB-chunked.
#define NUM_CLASSES 1024
#define NB 256              // hist / norm_scatter blocks
#define NSB 512             // bucket_sum blocks (64 per bucket)
#define BPB 64              // bucket_sum blocks per bucket

__device__ __forceinline__ int detect_mode32(const int* __restrict__ l) {
    return (l[1] | l[3] | l[5] | l[7] | l[9] | l[11] | l[13] | l[15]) != 0;
}
__device__ __forceinline__ int get_label(const int* __restrict__ l, int i, int mode32) {
    return l[mode32 ? i : (i << 1)] & (NUM_CLASSES - 1);
}
__device__ __forceinline__ unsigned bf16rne(float x) {
    unsigned u = __float_as_uint(x);
    return (u + 0x7FFFu + ((u >> 16) & 1u)) >> 16;
}
__device__ __forceinline__ unsigned packbf(float a, float b) {
    return bf16rne(a) | (bf16rne(b) << 16);
}
__device__ __forceinline__ float unpack_lo(unsigned u) { return __uint_as_float(u << 16); }
__device__ __forceinline__ float unpack_hi(unsigned u) { return __uint_as_float(u & 0xffff0000u); }

// ---- Kernel 1: per-block class partials + per-block bucket counts ----
__global__ void hist_kernel(const int* __restrict__ labels, int n, int chunk,
                            int* __restrict__ pT,          // [C][NB]
                            int* __restrict__ bh) {        // [8][NB]
    __shared__ int h[NUM_CLASSES];
    const int mode32 = detect_mode32(labels);
    for (int i = threadIdx.x; i < NUM_CLASSES; i += blockDim.x) h[i] = 0;
    __syncthreads();
    const int base = blockIdx.x * chunk;
    for (int k = threadIdx.x; k < chunk; k += blockDim.x) {
        int i = base + k;
        if (i < n) atomicAdd(&h[get_label(labels, i, mode32)], 1);
    }
    __syncthreads();
    for (int c = threadIdx.x; c < NUM_CLASSES; c += blockDim.x)
        pT[c * NB + blockIdx.x] = h[c];
    if (threadIdx.x < 8) {
        int s = 0;
        #pragma unroll 16
        for (int k = 0; k < 128; k++) s += h[threadIdx.x * 128 + k];
        bh[threadIdx.x * NB + blockIdx.x] = s;
    }
}

// ---- Kernel 2: per-class totals (contention-free) ----
__global__ void counts_kernel(const int* __restrict__ pT, int* __restrict__ counts) {
    const int c = blockIdx.x * 128 + threadIdx.x;     // grid 8 x 128
    int s = 0;
    for (int b = 0; b < NB; b++) s += pT[c * NB + b];
    counts[c] = s;
}

// ---- Kernel 3: scan bucket partials -> per-(block,bucket) write bases ----
__global__ __launch_bounds__(1024) void scanBH_kernel(int* __restrict__ bh,
        int* __restrict__ meta,          // [0..7]=bucketBase, [8..15]=bucketTotal
        float* __restrict__ accum, int* __restrict__ ticket) {
    __shared__ int tmp[1024];
    __shared__ int base[9];
    const int t = threadIdx.x;
    const int q = t >> 7, j = t & 127;   // pair j covers blocks 2j, 2j+1 of bucket q
    const int a0 = bh[q * NB + 2 * j];
    const int a1 = bh[q * NB + 2 * j + 1];
    const int s = a0 + a1;
    tmp[t] = s;
    __syncthreads();
    for (int off = 1; off < 128; off <<= 1) {
        int add = (j >= off) ? tmp[t - off] : 0;
        __syncthreads();
        tmp[t] += add;
        __syncthreads();
    }
    if (t == 0) {
        base[0] = 0;
        for (int qq = 0; qq < 8; qq++) {
            int tot = tmp[qq * 128 + 127];
            meta[8 + qq] = tot;
            meta[qq] = base[qq];
            base[qq + 1] = base[qq] + tot;
        }
        accum[0] = 0.0f; accum[1] = 0.0f; *ticket = 0;
    }
    __syncthreads();
    const int pairExcl = tmp[t] - s;
    bh[q * NB + 2 * j]     = base[q] + pairExcl;
    bh[q * NB + 2 * j + 1] = base[q] + pairExcl + a0;
}

// ---- Kernel 4: sequential read + normalize + bucket-chunked bf16 write ----
// 16 lanes/row (2 x float4), 4 rows per wave-iter. Each block's writes per
// bucket form one contiguous ~32 KB chunk (page-local) -> no translation wall.
__global__ __launch_bounds__(512) void norm_scatter_kernel(
        const float* __restrict__ emb, const int* __restrict__ labels,
        int n, int chunk,
        const int* __restrict__ bh,
        uint4* __restrict__ nbuf,            // bucket-grouped bf16 rows, 256 B each
        unsigned char* __restrict__ slot8) { // class low-7-bits per stored row
    __shared__ int cur[8];
    const int mode32 = detect_mode32(labels);
    if (threadIdx.x < 8) cur[threadIdx.x] = bh[threadIdx.x * NB + blockIdx.x];
    __syncthreads();
    const int lane = threadIdx.x & 63;
    const int wave = threadIdx.x >> 6;
    const int g    = lane >> 4;
    const int sub  = lane & 15;
    const int base = blockIdx.x * chunk;

    for (int r = wave * 4 + g; r < chunk; r += 32) {
        const int row = base + r;
        if (row < n) {
            const int lab = get_label(labels, row, mode32);
            const int q = lab >> 7;
            int pos = 0;
            if (sub == 0) pos = atomicAdd(&cur[q], 1);   // LDS atomic, 8 addrs
            pos = __shfl(pos, lane & ~15, 64);           // broadcast from leader
            const float4* rp = (const float4*)(emb + (size_t)row * 128);
            float4 v0 = rp[sub];
            float4 v1 = rp[sub + 16];
            float sq = v0.x*v0.x + v0.y*v0.y + v0.z*v0.z + v0.w*v0.w
                     + v1.x*v1.x + v1.y*v1.y + v1.z*v1.z + v1.w*v1.w;
            sq += __shfl_xor(sq, 1, 64);
            sq += __shfl_xor(sq, 2, 64);
            sq += __shfl_xor(sq, 4, 64);
            sq += __shfl_xor(sq, 8, 64);
            float inv = 1.0f / fmaxf(sqrtf(sq), 1e-12f);
            uint4 w;
            w.x = packbf(v0.x * inv, v0.y * inv);
            w.y = packbf(v0.z * inv, v0.w * inv);
            w.z = packbf(v1.x * inv, v1.y * inv);
            w.w = packbf(v1.z * inv, v1.w * inv);
            nbuf[(size_t)pos * 16 + sub] = w;
            if (sub == 0) slot8[pos] = (unsigned char)(lab & 127);
        }
    }
}

// ---- Kernel 5: stream bucket region, accumulate into 64 KB LDS table ----
// L[slot][dim] fp32, LDS float atomics. 2 blocks/CU. Writes 64 KB partials.
__global__ __launch_bounds__(512) void bucket_sum_kernel(
        const unsigned* __restrict__ nbuf32,    // 64 uints per row
        const unsigned char* __restrict__ slot8,
        const int* __restrict__ meta,
        float* __restrict__ partials) {         // [NSB][128*128]
    __shared__ float L[128 * 128];              // 64 KB
    for (int t = threadIdx.x; t < 128 * 128; t += blockDim.x) L[t] = 0.0f;
    __syncthreads();
    const int q = blockIdx.x >> 6;
    const int j = blockIdx.x & (BPB - 1);
    const int tot = meta[8 + q];
    const int chunk = (tot + BPB - 1) / BPB;
    const int lo = meta[q] + j * chunk;
    const int hi = min(lo + chunk, meta[q] + tot);
    const int wave = threadIdx.x >> 6;
    const int lane = threadIdx.x & 63;

    for (int row = lo + wave; row < hi; row += 8) {
        const int slot = slot8[row];                       // broadcast byte load
        const unsigned u = nbuf32[(size_t)row * 64 + lane]; // 256 B coalesced
        atomicAdd(&L[slot * 128 + 2 * lane],     unpack_lo(u));
        atomicAdd(&L[slot * 128 + 2 * lane + 1], unpack_hi(u));
    }
    __syncthreads();
    float* dst = partials + (size_t)blockIdx.x * 128 * 128;
    for (int t = threadIdx.x; t < 128 * 128; t += blockDim.x) dst[t] = L[t];
}

// ---- Kernel 6: combine partials -> per-class loss -> final scalar ----
__global__ __launch_bounds__(128) void combine_kernel(
        const float* __restrict__ partials,
        const int* __restrict__ counts,
        float* __restrict__ accum, int* __restrict__ ticket,
        float* __restrict__ out) {
    const int c = blockIdx.x;
    const int q = c >> 7;
    const int slot = c & 127;
    const int t = threadIdx.x;                  // dim 0..127
    float s = 0.0f;
    #pragma unroll 8
    for (int b = 0; b < BPB; b++)
        s += partials[((size_t)(q * BPB + b) * 128 + slot) * 128 + t];
    float x = s * s;
    #pragma unroll
    for (int off = 32; off; off >>= 1) x += __shfl_xor(x, off, 64);
    __shared__ float r2[2];
    const int lane = t & 63;
    if (lane == 0) r2[t >> 6] = x;
    __syncthreads();
    if (t == 0) {
        float tot = r2[0] + r2[1];
        const int count = counts[c];
        if (count >= 2) {
            float nrm = sqrtf(tot);             // = sum over class of sim
            float per_class = ((float)count - nrm) / (float)count;
            atomicAdd(&accum[0], per_class);
            atomicAdd(&accum[1], 1.0f);
        }
        __threadfence();
        int old = atomicAdd(ticket, 1);
        if (old == NUM_CLASSES - 1) {
            float ls = atomicAdd(&accum[0], 0.0f);   // device-scope reads
            float nv = atomicAdd(&accum[1], 0.0f);
            out[0] = (nv > 0.0f) ? (ls / nv) : 0.0f;
        }
    }
}

extern "C" void kernel_launch(void* const* d_in, const int* in_sizes, int n_in,
                              void* d_out, int out_size, void* d_ws, size_t ws_size,
                              hipStream_t stream) {
    const float* emb  = (const float*)d_in[0];
    const int* labels = (const int*)d_in[1];
    const int n = in_sizes[1];                       // 262144
    const int chunk = (n + NB - 1) / NB;             // 1024

    // Workspace (ws is 512 MiB — the harness poison fills 5.369e8 B; we use ~108 MB)
    char* ws = (char*)d_ws;
    int*   counts  = (int*)(ws + 0);                        // 4 KB
    int*   bh      = (int*)(ws + 4096);                     // 8*NB ints (8 KB)
    int*   meta    = (int*)(ws + 12352);                    // 16 ints
    float* accum   = (float*)(ws + 12480);                  // 2 floats
    int*   ticket  = (int*)(ws + 12496);                    // 1 int
    int*   pT      = (int*)(ws + 16384);                    // C*NB ints (1 MB)
    unsigned char* slot8 = (unsigned char*)(ws + (2u << 20));   // n bytes
    uint4* nbuf    = (uint4*)(ws + (4u << 20));             // n*256 B (64 MB)
    float* partials= (float*)(ws + (72u << 20));            // NSB*64 KB (32 MB)

    hist_kernel  <<<NB, 256, 0, stream>>>(labels, n, chunk, pT, bh);
    counts_kernel<<<8, 128, 0, stream>>>(pT, counts);
    scanBH_kernel<<<1, 1024, 0, stream>>>(bh, meta, accum, ticket);
    norm_scatter_kernel<<<NB, 512, 0, stream>>>(emb, labels, n, chunk, bh, nbuf, slot8);
    bucket_sum_kernel<<<NSB, 512, 0, stream>>>((const unsigned*)nbuf, slot8, meta, partials);
    combine_kernel<<<NUM_CLASSES, 128, 0, stream>>>(partials, counts, accum, ticket,
                                                    (float*)d_out);
}

// Round 9
// 295.698 us; speedup vs baseline: 1.5098x; 1.5098x over previous
//
#include <hip/hip_runtime.h>
#include <math.h>

// N=262144, D=128, C=1024. Embeddings fp32, output fp32 scalar, labels int32
// (int64 tolerated via uniform high-word probe).
//
// Established walls on this machine:
//  - ~262K random 256-512 B accesses over >64 MB cost ~90-100 us regardless of
//    direction or MLP (R3/R5/R6/R7): ~1.5 TB/s logical ceiling.
//  - Per-element LDS atomics saturate at ~0.75/cy/CU (R8: 33.5M atomics = 175 us).
// This design has NO fine-grained random global access and NO per-element
// atomics: 64 buckets x 16 classes; bucket_sum uses per-WAVE private 8 KB LDS
// tables (8 waves = 64 KB) with plain read-add-write.
#define NUM_CLASSES 1024
#define NBUCKET 64
#define NB 256              // hist / norm_scatter blocks
#define BSB 8               // bucket_sum blocks per bucket
#define NSB (NBUCKET * BSB) // 512

__device__ __forceinline__ int detect_mode32(const int* __restrict__ l) {
    return (l[1] | l[3] | l[5] | l[7] | l[9] | l[11] | l[13] | l[15]) != 0;
}
__device__ __forceinline__ int get_label(const int* __restrict__ l, int i, int mode32) {
    return l[mode32 ? i : (i << 1)] & (NUM_CLASSES - 1);
}
__device__ __forceinline__ unsigned bf16rne(float x) {
    unsigned u = __float_as_uint(x);
    return (u + 0x7FFFu + ((u >> 16) & 1u)) >> 16;
}
__device__ __forceinline__ unsigned packbf(float a, float b) {
    return bf16rne(a) | (bf16rne(b) << 16);
}
__device__ __forceinline__ float unpack_lo(unsigned u) { return __uint_as_float(u << 16); }
__device__ __forceinline__ float unpack_hi(unsigned u) { return __uint_as_float(u & 0xffff0000u); }

// ---- Kernel 1: per-block class partials + per-block bucket counts ----
__global__ void hist_kernel(const int* __restrict__ labels, int n, int chunk,
                            int* __restrict__ pT,          // [C][NB]
                            int* __restrict__ bh) {        // [NBUCKET][NB]
    __shared__ int h[NUM_CLASSES];
    const int mode32 = detect_mode32(labels);
    for (int i = threadIdx.x; i < NUM_CLASSES; i += blockDim.x) h[i] = 0;
    __syncthreads();
    const int base = blockIdx.x * chunk;
    for (int k = threadIdx.x; k < chunk; k += blockDim.x) {
        int i = base + k;
        if (i < n) atomicAdd(&h[get_label(labels, i, mode32)], 1);
    }
    __syncthreads();
    for (int c = threadIdx.x; c < NUM_CLASSES; c += blockDim.x)
        pT[c * NB + blockIdx.x] = h[c];
    if (threadIdx.x < NBUCKET) {
        int s = 0;
        #pragma unroll
        for (int k = 0; k < 16; k++) s += h[threadIdx.x * 16 + k];
        bh[threadIdx.x * NB + blockIdx.x] = s;
    }
}

// ---- Kernel 2: per-class totals ----
__global__ void counts_kernel(const int* __restrict__ pT, int* __restrict__ counts) {
    const int c = blockIdx.x * 128 + threadIdx.x;     // grid 8 x 128
    int s = 0;
    for (int b = 0; b < NB; b++) s += pT[c * NB + b];
    counts[c] = s;
}

// ---- Kernel 3: per-bucket exclusive scan along blocks (1 wave per bucket) ----
__global__ __launch_bounds__(64) void scanBH_kernel(int* __restrict__ bh,
                                                    int* __restrict__ qtot) {
    const int q = blockIdx.x;             // 64 blocks
    const int t = threadIdx.x;            // 64 threads = 1 wave
    int* p = bh + q * NB;
    int e0 = p[4*t], e1 = p[4*t+1], e2 = p[4*t+2], e3 = p[4*t+3];
    int s = e0 + e1 + e2 + e3;
    int inc = s;
    #pragma unroll
    for (int d = 1; d < 64; d <<= 1) {
        int v = __shfl_up(inc, d, 64);
        if (t >= d) inc += v;
    }
    int ex = inc - s;
    p[4*t]   = ex;
    p[4*t+1] = ex + e0;
    p[4*t+2] = ex + e0 + e1;
    p[4*t+3] = ex + e0 + e1 + e2;
    if (t == 63) qtot[q] = inc;
}

// ---- Kernel 4: bucket bases + zero accum/ticket (1 wave) ----
__global__ __launch_bounds__(64) void scanQ_kernel(const int* __restrict__ qtot,
                                                   int* __restrict__ qbase,
                                                   float* __restrict__ accum,
                                                   int* __restrict__ ticket) {
    const int t = threadIdx.x;
    int v = qtot[t];
    int inc = v;
    #pragma unroll
    for (int d = 1; d < 64; d <<= 1) {
        int u = __shfl_up(inc, d, 64);
        if (t >= d) inc += u;
    }
    qbase[t] = inc - v;
    if (t == 0) { accum[0] = 0.0f; accum[1] = 0.0f; *ticket = 0; }
}

// ---- Kernel 5: sequential read + normalize + bucket-chunked bf16 write ----
// 16 lanes/row, 4 rows/wave-iter. Block's writes per bucket are consecutive
// positions (64 advancing streams per block; ~16 rows = 4 KB per stream).
__global__ __launch_bounds__(512) void norm_scatter_kernel(
        const float* __restrict__ emb, const int* __restrict__ labels,
        int n, int chunk,
        const int* __restrict__ bh, const int* __restrict__ qbase,
        uint4* __restrict__ nbuf,            // bucket-grouped bf16 rows, 256 B
        unsigned char* __restrict__ slot8) { // class low-4-bits per stored row
    __shared__ int cur[NBUCKET];
    const int mode32 = detect_mode32(labels);
    if (threadIdx.x < NBUCKET)
        cur[threadIdx.x] = qbase[threadIdx.x] + bh[threadIdx.x * NB + blockIdx.x];
    __syncthreads();
    const int lane = threadIdx.x & 63;
    const int wave = threadIdx.x >> 6;
    const int g    = lane >> 4;
    const int sub  = lane & 15;
    const int base = blockIdx.x * chunk;

    for (int r = wave * 4 + g; r < chunk; r += 32) {
        const int row = base + r;
        if (row < n) {
            const int lab = get_label(labels, row, mode32);
            const int q = lab >> 4;
            int pos = 0;
            if (sub == 0) pos = atomicAdd(&cur[q], 1);   // LDS atomic, 1/row
            pos = __shfl(pos, lane & ~15, 64);           // broadcast from leader
            const float4* rp = (const float4*)(emb + (size_t)row * 128);
            float4 v0 = rp[sub];
            float4 v1 = rp[sub + 16];
            float sq = v0.x*v0.x + v0.y*v0.y + v0.z*v0.z + v0.w*v0.w
                     + v1.x*v1.x + v1.y*v1.y + v1.z*v1.z + v1.w*v1.w;
            sq += __shfl_xor(sq, 1, 64);
            sq += __shfl_xor(sq, 2, 64);
            sq += __shfl_xor(sq, 4, 64);
            sq += __shfl_xor(sq, 8, 64);
            float inv = 1.0f / fmaxf(sqrtf(sq), 1e-12f);
            uint4 w;
            w.x = packbf(v0.x * inv, v0.y * inv);
            w.y = packbf(v0.z * inv, v0.w * inv);
            w.z = packbf(v1.x * inv, v1.y * inv);
            w.w = packbf(v1.z * inv, v1.w * inv);
            nbuf[(size_t)pos * 16 + sub] = w;
            if (sub == 0) slot8[pos] = (unsigned char)(lab & 15);
        }
    }
}

// ---- Kernel 6: stream bucket region into per-WAVE private LDS tables ----
// No atomics: wave w owns Lw[w][16][128] (8 KB); row read is 256 B coalesced;
// per row: 1 LDS read-pair + add + write-pair per lane. Cross-wave reduce at end.
__global__ __launch_bounds__(512) void bucket_sum_kernel(
        const unsigned* __restrict__ nbuf32,    // 64 uints per row
        const unsigned char* __restrict__ slot8,
        const int* __restrict__ qtot, const int* __restrict__ qbase,
        float* __restrict__ partials) {         // [NSB][16][128]
    __shared__ float Lw[8][16][128];            // 64 KB
    for (int t = threadIdx.x; t < 8 * 16 * 128; t += blockDim.x)
        ((float*)Lw)[t] = 0.0f;
    __syncthreads();
    const int q   = blockIdx.x >> 3;
    const int j   = blockIdx.x & (BSB - 1);
    const int tot = qtot[q];
    const int beg = qbase[q];
    const int chunk = (tot + BSB - 1) / BSB;
    const int lo = beg + j * chunk;
    const int hi = min(lo + chunk, beg + tot);
    const int wave = threadIdx.x >> 6;
    const int lane = threadIdx.x & 63;

    for (int row = lo + wave; row < hi; row += 8) {
        const int slot = slot8[row];                         // broadcast load
        const unsigned u = nbuf32[(size_t)row * 64 + lane];  // 256 B coalesced
        float* Lp = &Lw[wave][slot][2 * lane];
        Lp[0] += unpack_lo(u);                               // plain LDS RMW
        Lp[1] += unpack_hi(u);
    }
    __syncthreads();
    float* dst = partials + (size_t)blockIdx.x * 16 * 128;
    for (int t = threadIdx.x; t < 16 * 128; t += blockDim.x) {
        float s = 0.0f;
        #pragma unroll
        for (int w = 0; w < 8; w++) s += Lw[w][0][t];
        dst[t] = s;
    }
}

// ---- Kernel 7: combine partials -> per-class loss -> final scalar ----
__global__ __launch_bounds__(128) void combine_kernel(
        const float* __restrict__ partials,
        const int* __restrict__ counts,
        float* __restrict__ accum, int* __restrict__ ticket,
        float* __restrict__ out) {
    const int c = blockIdx.x;
    const int q = c >> 4;
    const int slot = c & 15;
    const int t = threadIdx.x;                  // dim 0..127
    float s = 0.0f;
    #pragma unroll
    for (int b = 0; b < BSB; b++)
        s += partials[((size_t)(q * BSB + b) * 16 + slot) * 128 + t];
    float x = s * s;
    #pragma unroll
    for (int off = 32; off; off >>= 1) x += __shfl_xor(x, off, 64);
    __shared__ float r2[2];
    if ((t & 63) == 0) r2[t >> 6] = x;
    __syncthreads();
    if (t == 0) {
        float tot = r2[0] + r2[1];
        const int count = counts[c];
        if (count >= 2) {
            float nrm = sqrtf(tot);             // = sum over class of sim
            float per_class = ((float)count - nrm) / (float)count;
            atomicAdd(&accum[0], per_class);
            atomicAdd(&accum[1], 1.0f);
        }
        __threadfence();
        int old = atomicAdd(ticket, 1);
        if (old == NUM_CLASSES - 1) {
            float ls = atomicAdd(&accum[0], 0.0f);   // device-scope reads
            float nv = atomicAdd(&accum[1], 0.0f);
            out[0] = (nv > 0.0f) ? (ls / nv) : 0.0f;
        }
    }
}

extern "C" void kernel_launch(void* const* d_in, const int* in_sizes, int n_in,
                              void* d_out, int out_size, void* d_ws, size_t ws_size,
                              hipStream_t stream) {
    const float* emb  = (const float*)d_in[0];
    const int* labels = (const int*)d_in[1];
    const int n = in_sizes[1];                       // 262144
    const int chunk = (n + NB - 1) / NB;             // 1024

    // Workspace (~76 MB of the 512 MiB ws)
    char* ws = (char*)d_ws;
    int*   counts  = (int*)(ws + 0);                        // 4 KB
    int*   pT      = (int*)(ws + 8192);                     // C*NB ints (1 MB)
    int*   bh      = (int*)(ws + 8192 + (1u << 20));        // 64*NB ints (64 KB)
    int*   qtot    = (int*)(ws + 8192 + (1u << 20) + 65536);
    int*   qbase   = (int*)(ws + 8192 + (1u << 20) + 65536 + 256);
    float* accum   = (float*)(ws + 8192 + (1u << 20) + 65536 + 512);
    int*   ticket  = (int*)(ws + 8192 + (1u << 20) + 65536 + 520);
    unsigned char* slot8 = (unsigned char*)(ws + (2u << 20));   // n bytes
    uint4* nbuf    = (uint4*)(ws + (4u << 20));             // n*256 B (64 MB)
    float* partials= (float*)(ws + (72u << 20));            // NSB*8 KB (4 MB)

    hist_kernel  <<<NB, 256, 0, stream>>>(labels, n, chunk, pT, bh);
    counts_kernel<<<8, 128, 0, stream>>>(pT, counts);
    scanBH_kernel<<<NBUCKET, 64, 0, stream>>>(bh, qtot);
    scanQ_kernel <<<1, 64, 0, stream>>>(qtot, qbase, accum, ticket);
    norm_scatter_kernel<<<NB, 512, 0, stream>>>(emb, labels, n, chunk, bh, qbase,
                                                nbuf, slot8);
    bucket_sum_kernel<<<NSB, 512, 0, stream>>>((const unsigned*)nbuf, slot8,
                                               qtot, qbase, partials);
    combine_kernel<<<NUM_CLASSES, 128, 0, stream>>>(partials, counts, accum, ticket,
                                                    (float*)d_out);
}

// Round 10
// 275.697 us; speedup vs baseline: 1.6193x; 1.0725x over previous
//
#include <hip/hip_runtime.h>
#include <math.h>

// N=262144, D=128, C=1024. Embeddings fp32, output fp32 scalar, labels int32
// (int64 tolerated via uniform high-word probe).
//
// Wall model (R3/R5/R6/R7/R9): scattered 256-512 B row-ops run at ~2.7-3.3
// G rows/s (~11 G lines/s) vs 54 G lines/s sequential -> DRAM row-buffer
// locality, NOT latency/MLP (R7 disproved) and NOT translation. Fix: gather
// from a freshly-written 64 MB bf16 normalized copy (sequential write, in
// original row order) that is guaranteed Infinity-Cache-resident -> random
// reads become L3 SRAM hits with no page penalty.
#define NUM_CLASSES 1024
#define HIST_CHUNK 2048
#define NB 128                      // hist/scatter blocks

__device__ __forceinline__ int detect_mode32(const int* __restrict__ l) {
    return (l[1] | l[3] | l[5] | l[7] | l[9] | l[11] | l[13] | l[15]) != 0;
}
__device__ __forceinline__ int get_label(const int* __restrict__ l, int i, int mode32) {
    return l[mode32 ? i : (i << 1)] & (NUM_CLASSES - 1);
}
__device__ __forceinline__ unsigned bf16rne(float x) {
    unsigned u = __float_as_uint(x);
    return (u + 0x7FFFu + ((u >> 16) & 1u)) >> 16;
}
__device__ __forceinline__ unsigned packbf(float a, float b) {
    return bf16rne(a) | (bf16rne(b) << 16);
}
__device__ __forceinline__ float unpack_lo(unsigned u) { return __uint_as_float(u << 16); }
__device__ __forceinline__ float unpack_hi(unsigned u) { return __uint_as_float(u & 0xffff0000u); }

// ---------------- Kernel 1: per-block partial histograms (R5, proven) ----------------
__global__ void hist_kernel(const int* __restrict__ labels, int n,
                            int* __restrict__ pT) {        // [C][NB]
    __shared__ int h[NUM_CLASSES];
    const int mode32 = detect_mode32(labels);
    for (int i = threadIdx.x; i < NUM_CLASSES; i += blockDim.x) h[i] = 0;
    __syncthreads();
    const int base = blockIdx.x * HIST_CHUNK;
    for (int k = threadIdx.x; k < HIST_CHUNK; k += blockDim.x) {
        int i = base + k;
        if (i < n) atomicAdd(&h[get_label(labels, i, mode32)], 1);
    }
    __syncthreads();
    for (int c = threadIdx.x; c < NUM_CLASSES; c += blockDim.x)
        pT[c * NB + blockIdx.x] = h[c];
}

// ---------------- Kernel 2a: per-class prefix along blocks (R5, proven) ----------------
__global__ __launch_bounds__(512) void scanA_kernel(int* __restrict__ pT,
                                                    int* __restrict__ totals) {
    const int wave = threadIdx.x >> 6;
    const int lane = threadIdx.x & 63;
    const int c = blockIdx.x * 8 + wave;        // 128 blocks x 8 waves = 1024
    int* p = pT + c * NB;
    const int v0 = p[2 * lane];
    const int v1 = p[2 * lane + 1];
    int s = v0 + v1;
    #pragma unroll
    for (int d = 1; d < 64; d <<= 1) {
        int t = __shfl_up(s, d, 64);
        if (lane >= d) s += t;
    }
    const int base = s - v0 - v1;
    p[2 * lane]     = base;
    p[2 * lane + 1] = base + v0;
    if (lane == 63) totals[c] = s;
}

// ---------------- Kernel 2b: cross-class exclusive scan (R5, proven) ----------------
__global__ void scanB_kernel(const int* __restrict__ totals,
                             int* __restrict__ offsets,
                             int* __restrict__ counts,
                             float* __restrict__ accum,
                             int* __restrict__ ticket) {
    __shared__ int tmp[NUM_CLASSES];
    const int c = threadIdx.x;                  // blockDim.x == 1024
    const int v = totals[c];
    tmp[c] = v;
    __syncthreads();
    for (int off = 1; off < NUM_CLASSES; off <<= 1) {
        int add = (c >= off) ? tmp[c - off] : 0;
        __syncthreads();
        tmp[c] += add;
        __syncthreads();
    }
    offsets[c] = tmp[c] - v;
    counts[c]  = v;
    if (c == 0) { accum[0] = 0.0f; accum[1] = 0.0f; *ticket = 0; }
}

// ---------------- Kernel 3: scatter via LDS cursors (R5, proven) ----------------
__global__ void scatter_kernel(const int* __restrict__ labels, int n,
                               const int* __restrict__ pT,
                               const int* __restrict__ offsets,
                               int* __restrict__ sorted) {
    __shared__ int cur[NUM_CLASSES];
    const int mode32 = detect_mode32(labels);
    for (int c = threadIdx.x; c < NUM_CLASSES; c += blockDim.x)
        cur[c] = offsets[c] + pT[c * NB + blockIdx.x];
    __syncthreads();
    const int base = blockIdx.x * HIST_CHUNK;
    for (int k = threadIdx.x; k < HIST_CHUNK; k += blockDim.x) {
        int i = base + k;
        if (i < n) {
            int pos = atomicAdd(&cur[get_label(labels, i, mode32)], 1);  // LDS atomic
            sorted[pos] = i;
        }
    }
}

// ---------------- Kernel 4: SEQUENTIAL normalize -> bf16 copy (order-preserving) ----------------
// 16 lanes/row (2 x float4), 4 rows per wave-iter. Reads 128 MB sequential,
// writes nbuf[row] sequential (64 MB). Runs immediately before the gather so
// nbuf is the most-recently-written data in the 256 MB Infinity Cache.
__global__ __launch_bounds__(512) void norm_seq_kernel(
        const float* __restrict__ emb,      // N x 128 fp32
        uint4* __restrict__ nbuf,           // N rows x 256 B (16 x uint4)
        int n) {
    const int wave = threadIdx.x >> 6;
    const int lane = threadIdx.x & 63;
    const int g    = lane >> 4;
    const int sub  = lane & 15;
    const int base = blockIdx.x * 256;

    for (int r = wave * 4 + g; r < 256; r += 32) {
        const int row = base + r;
        if (row < n) {
            const float4* rp = (const float4*)(emb + (size_t)row * 128);
            float4 v0 = rp[sub];
            float4 v1 = rp[sub + 16];
            float sq = v0.x*v0.x + v0.y*v0.y + v0.z*v0.z + v0.w*v0.w
                     + v1.x*v1.x + v1.y*v1.y + v1.z*v1.z + v1.w*v1.w;
            sq += __shfl_xor(sq, 1, 64);
            sq += __shfl_xor(sq, 2, 64);
            sq += __shfl_xor(sq, 4, 64);
            sq += __shfl_xor(sq, 8, 64);
            float inv = 1.0f / fmaxf(sqrtf(sq), 1e-12f);
            uint4 w;
            w.x = packbf(v0.x * inv, v0.y * inv);
            w.y = packbf(v0.z * inv, v0.w * inv);
            w.z = packbf(v1.x * inv, v1.y * inv);
            w.w = packbf(v1.z * inv, v1.w * inv);
            nbuf[(size_t)row * 16 + sub] = w;   // sequential: same order as read
        }
    }
}

// ---------------- Kernel 5: per-class gather from L3-hot nbuf + loss (+finalize) ----------------
// One block (8 waves) per class, 1 row/wave/iter (R3's best-performing gather
// shape), 256 B row = 64 lanes x 4 B. Unroll-2 for 2 rows in flight.
// Identity: sum_{i in c} dot(emb_i, proto_c) = ||sum_{i in c} norm(emb_i)||,
// so per_class = (count - ||sum||) / count. Dim permutation in nbuf packing is
// irrelevant (norms are permutation-invariant; lane slot fixed across rows).
#define WPB 8
__global__ __launch_bounds__(512) void class_sum_kernel(
        const unsigned* __restrict__ nbuf32,   // N x 64 uints (bf16 pairs)
        const int* __restrict__ sorted,
        const int* __restrict__ offsets,
        const int* __restrict__ counts,
        float* __restrict__ accum,          // [0]=loss_sum, [1]=n_valid
        int* __restrict__ ticket,
        float* __restrict__ out) {
    const int c     = blockIdx.x;
    const int start = offsets[c];
    const int count = counts[c];
    const int wave  = threadIdx.x >> 6;
    const int lane  = threadIdx.x & 63;

    float a0 = 0.0f, a1 = 0.0f;
    int r = wave;
    for (; r + WPB < count; r += 2 * WPB) {
        const int i0 = sorted[start + r];
        const int i1 = sorted[start + r + WPB];
        const unsigned u0 = nbuf32[(size_t)i0 * 64 + lane];  // 256 B coalesced
        const unsigned u1 = nbuf32[(size_t)i1 * 64 + lane];
        a0 += unpack_lo(u0); a1 += unpack_hi(u0);
        a0 += unpack_lo(u1); a1 += unpack_hi(u1);
    }
    if (r < count) {
        const int i0 = sorted[start + r];
        const unsigned u0 = nbuf32[(size_t)i0 * 64 + lane];
        a0 += unpack_lo(u0); a1 += unpack_hi(u0);
    }

    // Reduce partial sums across the 8 waves (R5 epilogue, proven absmax 0)
    __shared__ float2 s2[WPB][64];
    s2[wave][lane] = make_float2(a0, a1);
    __syncthreads();

    __shared__ float red[128];
    if (threadIdx.x < 128) {
        int l = threadIdx.x >> 1;      // lane that held it
        int hi = threadIdx.x & 1;      // 0 -> a0, 1 -> a1
        float t = 0.0f;
        #pragma unroll
        for (int w = 0; w < WPB; w++) {
            float2 v = s2[w][l];
            t += hi ? v.y : v.x;
        }
        red[threadIdx.x] = t * t;
    }
    __syncthreads();
    if (threadIdx.x < 64) {
        float x = red[threadIdx.x] + red[threadIdx.x + 64];
        #pragma unroll
        for (int off = 32; off; off >>= 1) x += __shfl_xor(x, off, 64);
        if (threadIdx.x == 0) {
            if (count >= 2) {
                float nrm = sqrtf(x);                   // = sum over class of sim
                float per_class = ((float)count - nrm) / (float)count;
                atomicAdd(&accum[0], per_class);
                atomicAdd(&accum[1], 1.0f);
            }
            __threadfence();
            int old = atomicAdd(ticket, 1);
            if (old == NUM_CLASSES - 1) {
                float ls = atomicAdd(&accum[0], 0.0f);  // device-scope reads
                float nv = atomicAdd(&accum[1], 0.0f);
                out[0] = (nv > 0.0f) ? (ls / nv) : 0.0f;
            }
        }
    }
}

extern "C" void kernel_launch(void* const* d_in, const int* in_sizes, int n_in,
                              void* d_out, int out_size, void* d_ws, size_t ws_size,
                              hipStream_t stream) {
    const float* emb  = (const float*)d_in[0];
    const int* labels = (const int*)d_in[1];
    const int n = in_sizes[1];                   // 262144

    // Workspace (~70 MB of the 512 MiB ws)
    char* ws = (char*)d_ws;
    int*   counts  = (int*)(ws + 0);                       // 1024 ints
    int*   offsets = (int*)(ws + 4096);                    // 1024 ints
    int*   totals  = (int*)(ws + 8192);                    // 1024 ints
    float* accum   = (float*)(ws + 12288);                 // 2 floats
    int*   ticket  = (int*)(ws + 12304);                   // 1 int
    int*   sorted  = (int*)(ws + 16384);                   // n ints (1 MB)
    int*   pT      = (int*)(ws + 16384 + (size_t)n * 4);   // C*NB ints (512 KB)
    uint4* nbuf    = (uint4*)(ws + (4u << 20));            // n x 256 B (64 MB)

    hist_kernel <<<NB, 256, 0, stream>>>(labels, n, pT);
    scanA_kernel<<<NB, 512, 0, stream>>>(pT, totals);
    scanB_kernel<<<1, NUM_CLASSES, 0, stream>>>(totals, offsets, counts, accum, ticket);
    scatter_kernel<<<NB, 256, 0, stream>>>(labels, n, pT, offsets, sorted);
    norm_seq_kernel<<<(n + 255) / 256, 512, 0, stream>>>(emb, nbuf, n);
    class_sum_kernel<<<NUM_CLASSES, 512, 0, stream>>>((const unsigned*)nbuf, sorted,
                                                      offsets, counts,
                                                      accum, ticket, (float*)d_out);
}